// Round 21
// baseline (250.627 us; speedup 1.0000x reference)
//
#include <hip/hip_runtime.h>
#include <hip/hip_fp8.h>
#include <stdint.h>
#include <math.h>

// cdist-attention. R21: R20's 3-blocks/CU recipe applied to the bf16 trio.
// PV was top dispatch (67us, Occ 24.5%: 384 blocks = 1.5/CU + 4-waves cap).
// gemm128n: BM=128/BN=128/BK=32, acc[4][2]=32 regs, launch_bounds(512,6),
// LDS 32KB -> 3 blocks/CU. Tile = 128 rows x 64B == R20 fp8 tile byte-shape
// (staging/swizzle verbatim); b128 frag reads == gemm128b pattern (verified).
// Grids: PV 768 blocks (all-resident at 3/CU), QK 1536, VT 768.
// Scores gemm128f8 + rowreduces + casts byte-identical to R20.

typedef __attribute__((ext_vector_type(8))) __bf16 bf16x8;
typedef __attribute__((ext_vector_type(4))) float f32x4;
typedef __attribute__((ext_vector_type(4))) unsigned int u32x4;

__device__ __forceinline__ unsigned short f2b(float f) {
    unsigned u = __float_as_uint(f);
    unsigned r = 0x7fffu + ((u >> 16) & 1u);
    return (unsigned short)((u + r) >> 16);
}
__device__ __forceinline__ float b2f(unsigned short h) {
    return __uint_as_float(((unsigned)h) << 16);
}
__device__ __forceinline__ unsigned char f2f8(float f) {
    __hip_fp8_e4m3 t(f);
    return t.__x;
}
__device__ __forceinline__ float f8tof(unsigned char b) {
    int e = (b >> 3) & 15, m = b & 7;
    float v = e ? ldexpf(8.0f + m, e - 10) : ldexpf((float)m, -9);
    return (b & 0x80) ? -v : v;
}

__device__ __forceinline__ void wg_barrier() {
    asm volatile("" ::: "memory");
    __builtin_amdgcn_s_barrier();
    asm volatile("" ::: "memory");
}

__device__ __forceinline__ unsigned lds_off(const void* p) {
    return (unsigned)(uintptr_t)(const __attribute__((address_space(3))) char*)p;
}

__global__ __launch_bounds__(256) void castk(const float* __restrict__ src,
                                             unsigned short* __restrict__ dst, int n4) {
    int i = blockIdx.x * 256 + threadIdx.x;
    if (i >= n4) return;
    float4 v = ((const float4*)src)[i];
    ushort4 o;
    o.x = f2b(v.x); o.y = f2b(v.y); o.z = f2b(v.z); o.w = f2b(v.w);
    ((ushort4*)dst)[i] = o;
}

// MODE 0: row sum; MODE 1: row sum of squares. One wave per row (bf16 input).
template <int MODE>
__global__ __launch_bounds__(256) void rowreduce(const unsigned short* __restrict__ X,
                                                 int L, int rows, float* __restrict__ out) {
    int w = threadIdx.x >> 6, lane = threadIdx.x & 63;
    int row = blockIdx.x * 4 + w;
    if (row >= rows) return;
    const unsigned short* xr = X + (size_t)row * L;
    float s = 0.f;
    int passes = L >> 8;
    for (int p = 0; p < passes; ++p) {
        ushort4 u = *(const ushort4*)(xr + (p << 8) + lane * 4);
        float a = b2f(u.x), b = b2f(u.y), c = b2f(u.z), d = b2f(u.w);
        s += MODE ? (a * a + b * b + c * c + d * d) : (a + b + c + d);
    }
#pragma unroll
    for (int o = 32; o > 0; o >>= 1) s += __shfl_down(s, o);
    if (lane == 0) out[row] = s;
}

// row sum of squares over fp8-e4m3 rows
__global__ __launch_bounds__(256) void rowreduce8(const unsigned char* __restrict__ X,
                                                  int L, int rows, float* __restrict__ out) {
    int w = threadIdx.x >> 6, lane = threadIdx.x & 63;
    int row = blockIdx.x * 4 + w;
    if (row >= rows) return;
    const unsigned char* xr = X + (size_t)row * L;
    float s = 0.f;
    int passes = L >> 8;
    for (int p = 0; p < passes; ++p) {
        uchar4 u = *(const uchar4*)(xr + (p << 8) + lane * 4);
        float a = f8tof(u.x), b = f8tof(u.y), c = f8tof(u.z), d = f8tof(u.w);
        s += a * a + b * b + c * c + d * d;
    }
#pragma unroll
    for (int o = 32; o > 0; o >>= 1) s += __shfl_down(s, o);
    if (lane == 0) out[row] = s;
}

#define MF(A_, B_, C_) (C_) = __builtin_amdgcn_mfma_f32_16x16x32_bf16((A_), (B_), (C_), 0, 0, 0)
#define MF8(A_, B_, C_) (C_) = __builtin_amdgcn_mfma_f32_16x16x32_fp8_fp8((A_), (B_), (C_), 0, 0, 0)
#define DSR(dst_, a_, imm_) \
    asm volatile("ds_read_b128 %0, %1 offset:" #imm_ : "=v"(dst_) : "v"(a_))
#define DSR64(dst_, a_, imm_) \
    asm volatile("ds_read_b64 %0, %1 offset:" #imm_ : "=v"(dst_) : "v"(a_))
#define GL4(d_, p_) asm volatile("global_load_dwordx4 %0, %1, off" : "=v"(d_) : "v"(p_))
#define DSW(a_, imm_, d_) \
    asm volatile("ds_write_b128 %0, %1 offset:" #imm_ :: "v"(a_), "v"(d_) : "memory")
#define LGKM(n_) asm volatile("s_waitcnt lgkmcnt(" #n_ ")" ::: "memory")
#define VMC0 asm volatile("s_waitcnt vmcnt(0)" ::: "memory")
#define SB0 __builtin_amdgcn_sched_barrier(0)

// ------- bf16 GEMM, 128x128/BK=32, acc[4][2], 3 blocks/CU -------
// Tile: 128 rows x 64 B for A and B (same byte-shape as R20 fp8 tile).
// Staging: thread t -> row t>>2, stored 16B-slot t&3,
//   logical chunk clog = (t&3) ^ ((row>>1)&3)  (R5/R7-verified involution).
// Frag reads: byte = row*64 + ((kq ^ ((c16>>1)&3))<<4); mi/ni -> +1024 imm.
#define LOADTN(T_) do {                                                    \
    const size_t ko_ = (size_t)(T_) * 32;                                  \
    GL4(ra0, pa + ko_);                                                    \
    GL4(rb0, pb + ko_);                                                    \
} while (0)
#define WRITETN(WB_) do {                                                  \
    DSW(wAa + (WB_), 0, ra0);                                              \
    DSW(wBb + (WB_), 0, rb0);                                              \
} while (0)

// EPI 0: bf16 out. EPI 2: f32 = acc / aux1[row]. EPI 3: fp8-e4m3 out.
template <int EPI>
__global__ __launch_bounds__(512, 6) void gemm128n(
    const unsigned short* __restrict__ A, int lda, long long sA,
    const unsigned short* __restrict__ B, int ldb, long long sB,
    void* __restrict__ Cv, int ldc, long long sC,
    int Kd, int perm,
    const float* __restrict__ aux1, int sAux1) {
    __shared__ __attribute__((aligned(128))) unsigned short As[2 * 128 * 32];  // 16 KB
    __shared__ __attribute__((aligned(128))) unsigned short Bs[2 * 128 * 32];  // 16 KB

    const int z = perm ? blockIdx.x : blockIdx.z;
    const int jb = perm ? blockIdx.y : blockIdx.x;
    const int ib = perm ? blockIdx.z : blockIdx.y;
    const unsigned short* __restrict__ Ab = A + (size_t)z * sA;
    const unsigned short* __restrict__ Bb = B + (size_t)z * sB;
    const int i0 = ib * 128, j0 = jb * 128;
    const int tid = threadIdx.x;
    const int w = tid >> 6, lane = tid & 63;
    const int wr = w >> 2, wc = w & 3;   // 2M x 4N waves, 64x32 C each
    const int c16 = lane & 15, kq = lane >> 4;

    const int srow = tid >> 2;           // 0..127
    const int clog = (tid & 3) ^ ((srow >> 1) & 3);
    const unsigned short* pa = Ab + (size_t)(i0 + srow) * lda + clog * 8;
    const unsigned short* pb = Bb + (size_t)(j0 + srow) * ldb + clog * 8;

    const unsigned wAa = lds_off(As) + (unsigned)tid * 16;
    const unsigned wBb = lds_off(Bs) + (unsigned)tid * 16;

    const int sw = (kq ^ ((c16 >> 1) & 3)) << 4;
    const unsigned adrA0 = lds_off(As) + (unsigned)(wr * 64 + c16) * 64 + sw;
    const unsigned adrB0 = lds_off(Bs) + (unsigned)(wc * 32 + c16) * 64 + sw;

    f32x4 acc[4][2];
    const f32x4 zero = {0.f, 0.f, 0.f, 0.f};
#pragma unroll
    for (int i = 0; i < 4; ++i)
#pragma unroll
        for (int j = 0; j < 2; ++j) acc[i][j] = zero;

    u32x4 ra0, rb0;
    bf16x8 aF[4], bF[2];

    const int nt = Kd >> 5;  // BK=32 tiles

    LOADTN(0);
    VMC0;
    WRITETN(0u);
    LOADTN(1);
    LGKM(0);
    wg_barrier();

    for (int t = 0; t < nt; ++t) {
        const unsigned rb_ = (t & 1) ? 8192u : 0u;
        const unsigned wb_ = (t & 1) ? 0u : 8192u;
        const unsigned aA = adrA0 + rb_;
        const unsigned aB = adrB0 + rb_;
        DSR(aF[0], aA, 0);    DSR(aF[1], aA, 1024);
        DSR(aF[2], aA, 2048); DSR(aF[3], aA, 3072);
        DSR(bF[0], aB, 0);    DSR(bF[1], aB, 1024);
        if (t + 1 < nt) {
            VMC0;            // loads for t+1 issued one tile ago
            WRITETN(wb_);
            if (t + 2 < nt) LOADTN(t + 2);
            LGKM(2);         // 6 reads done; 2 writes may remain
        } else {
            LGKM(0);
        }
        SB0;
        __builtin_amdgcn_s_setprio(1);
#pragma unroll
        for (int mi = 0; mi < 4; ++mi)
#pragma unroll
            for (int ni = 0; ni < 2; ++ni)
                MF(aF[mi], bF[ni], acc[mi][ni]);
        __builtin_amdgcn_s_setprio(0);
        LGKM(0);             // publish writes before barrier
        wg_barrier();
    }

    const int prow = kq * 4;
    if constexpr (EPI == 0) {
        unsigned short* C = (unsigned short*)Cv + (size_t)z * sC;
#pragma unroll
        for (int mi = 0; mi < 4; ++mi)
#pragma unroll
            for (int ni = 0; ni < 2; ++ni) {
                const int row = i0 + wr * 64 + mi * 16 + prow;
                const int col = j0 + wc * 32 + ni * 16 + c16;
#pragma unroll
                for (int r = 0; r < 4; ++r)
                    C[(size_t)(row + r) * ldc + col] = f2b(acc[mi][ni][r]);
            }
    } else if constexpr (EPI == 3) {
        unsigned char* C = (unsigned char*)Cv + (size_t)z * sC;
#pragma unroll
        for (int mi = 0; mi < 4; ++mi)
#pragma unroll
            for (int ni = 0; ni < 2; ++ni) {
                const int row = i0 + wr * 64 + mi * 16 + prow;
                const int col = j0 + wc * 32 + ni * 16 + c16;
#pragma unroll
                for (int r = 0; r < 4; ++r)
                    C[(size_t)(row + r) * ldc + col] = f2f8(acc[mi][ni][r]);
            }
    } else {
        float* C = (float*)Cv + (size_t)z * sC;
        const float* lb = aux1 + (size_t)z * sAux1;
#pragma unroll
        for (int mi = 0; mi < 4; ++mi) {
            const int row = i0 + wr * 64 + mi * 16 + prow;
            float linv[4];
#pragma unroll
            for (int r = 0; r < 4; ++r) linv[r] = 1.0f / lb[row + r];
#pragma unroll
            for (int ni = 0; ni < 2; ++ni) {
                const int col = j0 + wc * 32 + ni * 16 + c16;
#pragma unroll
                for (int r = 0; r < 4; ++r)
                    C[(size_t)(row + r) * ldc + col] = acc[mi][ni][r] * linv[r];
            }
        }
    }
}

// -------- fp8 scores GEMM (R20, verified): BM=128 x BN=128, 3 blocks/CU --------
#define LOADT8(T_) do {                                                    \
    const size_t ko_ = (size_t)(T_) * 64;                                  \
    GL4(fa0, pa8 + ko_);                                                   \
    GL4(fb0, pb8 + ko_);                                                   \
} while (0)
#define WRITET8(WB_) do {                                                  \
    DSW(wA8 + (WB_), 0, fa0);                                              \
    DSW(wB8 + (WB_), 0, fb0);                                              \
} while (0)

__global__ __launch_bounds__(512, 6) void gemm128f8(
    const unsigned char* __restrict__ A, int lda, long long sA,
    const unsigned char* __restrict__ B, int ldb, long long sB,
    unsigned short* __restrict__ Cq, int ldc, long long sC,
    int Kd,
    const float* __restrict__ q2a, int sQ2,
    const float* __restrict__ k2a, int sK2,
    float invs) {
    __shared__ __attribute__((aligned(128))) unsigned char As8[2 * 128 * 64];  // 16 KB
    __shared__ __attribute__((aligned(128))) unsigned char Bs8[2 * 128 * 64];  // 16 KB

    const int z = blockIdx.x;        // XCD i owns batch i
    const int jb = blockIdx.y, ib = blockIdx.z;
    const unsigned char* __restrict__ Ab = A + (size_t)z * sA;
    const unsigned char* __restrict__ Bb = B + (size_t)z * sB;
    const int i0 = ib * 128, j0 = jb * 128;
    const int tid = threadIdx.x;
    const int w = tid >> 6, lane = tid & 63;
    const int wr = w >> 2, wc = w & 3;   // 2M x 4N waves, 64x32 C each
    const int c16 = lane & 15, kq = lane >> 4;

    const int srow = tid >> 2;           // 0..127
    const int p8 = (tid & 3) ^ (srow & 3) ^ ((srow >> 2) & 1);
    const unsigned char* pa8 = Ab + (size_t)(i0 + srow) * lda + p8 * 16;
    const unsigned char* pb8 = Bb + (size_t)(j0 + srow) * ldb + p8 * 16;

    const unsigned wA8 = lds_off(As8) + (unsigned)tid * 16;
    const unsigned wB8 = lds_off(Bs8) + (unsigned)tid * 16;

    const int gl = (c16 & 3) ^ ((c16 >> 2) & 1);
    const int soff = ((((kq >> 1) ^ gl) << 4) | ((kq & 1) << 3));
    const unsigned adrA80 = lds_off(As8) + (unsigned)(wr * 64 + c16) * 64 + soff;
    const unsigned adrB80 = lds_off(Bs8) + (unsigned)(wc * 32 + c16) * 64 + soff;

    f32x4 acc[4][2];
    const f32x4 zero = {0.f, 0.f, 0.f, 0.f};
#pragma unroll
    for (int i = 0; i < 4; ++i)
#pragma unroll
        for (int j = 0; j < 2; ++j) acc[i][j] = zero;

    u32x4 fa0, fb0;
    long aF[4][2], bF[2][2];

    const int nt = Kd >> 6;  // 12

    LOADT8(0);
    VMC0;
    WRITET8(0u);
    LOADT8(1);
    LGKM(0);
    wg_barrier();

    for (int t = 0; t < nt; ++t) {
        const unsigned rb_ = (t & 1) ? 8192u : 0u;
        const unsigned wb_ = (t & 1) ? 0u : 8192u;
        const unsigned aA = adrA80 + rb_, aAx = aA ^ 32u;
        const unsigned aB = adrB80 + rb_, aBx = aB ^ 32u;
        DSR64(aF[0][0], aA, 0);    DSR64(aF[0][1], aAx, 0);
        DSR64(aF[1][0], aA, 1024); DSR64(aF[1][1], aAx, 1024);
        DSR64(aF[2][0], aA, 2048); DSR64(aF[2][1], aAx, 2048);
        DSR64(aF[3][0], aA, 3072); DSR64(aF[3][1], aAx, 3072);
        DSR64(bF[0][0], aB, 0);    DSR64(bF[0][1], aBx, 0);
        DSR64(bF[1][0], aB, 1024); DSR64(bF[1][1], aBx, 1024);
        if (t + 1 < nt) {
            VMC0;
            WRITET8(wb_);
            if (t + 2 < nt) LOADT8(t + 2);
            LGKM(2);
        } else {
            LGKM(0);
        }
        SB0;
        __builtin_amdgcn_s_setprio(1);
#pragma unroll
        for (int kk = 0; kk < 2; ++kk)
#pragma unroll
            for (int mi = 0; mi < 4; ++mi)
#pragma unroll
                for (int ni = 0; ni < 2; ++ni)
                    MF8(aF[mi][kk], bF[ni][kk], acc[mi][ni]);
        __builtin_amdgcn_s_setprio(0);
        LGKM(0);
        wg_barrier();
    }

    // scores epilogue: E -> bf16 via per-wave transpose (16x40 shorts in dead As8)
    unsigned short* C = Cq + (size_t)z * sC;
    const float* q2b = q2a + (size_t)z * sQ2;
    const float* k2b = k2a + (size_t)z * sK2;
    unsigned short* sc = (unsigned short*)(As8 + w * 2048);
    const int prow = kq * 4;
    const int rr = lane >> 2, ch = lane & 3;
#pragma unroll
    for (int mi = 0; mi < 4; ++mi) {
#pragma unroll
        for (int ni = 0; ni < 2; ++ni) {
            const int col = j0 + wc * 32 + ni * 16 + c16;
            const float k2v = k2b[col];
#pragma unroll
            for (int r = 0; r < 4; ++r) {
                const int grow = i0 + wr * 64 + mi * 16 + prow + r;
                float d2 = q2b[grow] + k2v - 2.0f * acc[mi][ni][r];
                float e = __expf(sqrtf(fmaxf(d2, 0.f)) * invs);
                sc[(prow + r) * 40 + ni * 16 + c16] = f2b(e);
            }
        }
        bf16x8 v = *(const bf16x8*)&sc[rr * 40 + ch * 8];
        const int grow = i0 + wr * 64 + mi * 16 + rr;
        *(bf16x8*)&C[(size_t)grow * ldc + j0 + wc * 32 + ch * 8] = v;
    }
}

extern "C" void kernel_launch(void* const* d_in, const int* in_sizes, int n_in,
                              void* d_out, int out_size, void* d_ws, size_t ws_size,
                              hipStream_t stream) {
    const float* x = (const float*)d_in[0];
    const float* Wq = (const float*)d_in[1];
    const float* Wk = (const float*)d_in[2];
    const float* Wv = (const float*)d_in[3];
    const int Bz = 8, S = 2048, D = 768, F = 768;
    const int BS = Bz * S;  // 16384

    const size_t szX = (size_t)BS * D * 2;
    const size_t szW = (size_t)F * D * 2;
    const size_t szQ8 = (size_t)BS * F;
    const size_t szE = (size_t)Bz * S * S * 2;

    char* p = (char*)d_ws;
    unsigned short* xb = (unsigned short*)p;  p += szX;
    unsigned short* Wqb = (unsigned short*)p; p += szW;
    unsigned short* Wkb = (unsigned short*)p; p += szW;
    unsigned short* Wvb = (unsigned short*)p; p += szW;
    unsigned char* Q8 = (unsigned char*)p;    p += szQ8;
    unsigned char* K8 = (unsigned char*)p;    p += szQ8;
    unsigned short* VT = (unsigned short*)p;  p += szX;   // [F][BS]
    unsigned short* E = (unsigned short*)p;   p += szE;   // [Bz][S][S]
    float* q2 = (float*)p;    p += (size_t)BS * 4;
    float* k2 = (float*)p;    p += (size_t)BS * 4;
    float* lsum = (float*)p;  p += (size_t)BS * 4;
    if ((size_t)(p - (char*)d_ws) > ws_size) return;  // ~147 MiB scratch required

    const float invs = 1.0f / sqrtf(768.0f);

    // 1) casts
    castk<<<(BS * D / 4 + 255) / 256, 256, 0, stream>>>(x, xb, BS * D / 4);
    castk<<<(F * D / 4 + 255) / 256, 256, 0, stream>>>(Wq, Wqb, F * D / 4);
    castk<<<(F * D / 4 + 255) / 256, 256, 0, stream>>>(Wk, Wkb, F * D / 4);
    castk<<<(F * D / 4 + 255) / 256, 256, 0, stream>>>(Wv, Wvb, F * D / 4);

    // 2) Q8,K8 = e4m3(x . W^T)  (z=0 -> Wq->Q8, z=1 -> Wk->K8); 1536 blocks
    gemm128n<3><<<dim3(F / 128, BS / 128, 2), 512, 0, stream>>>(
        xb, D, 0,
        Wqb, D, (long long)F * D,
        Q8, F, (long long)BS * F,
        D, 0, nullptr, 0);

    //    V^T = Wv . x^T -> VT[f][s] (bf16); 768 blocks
    gemm128n<0><<<dim3(BS / 128, F / 128, 1), 512, 0, stream>>>(
        Wvb, D, 0,
        xb, D, 0,
        VT, BS, 0,
        D, 0, nullptr, 0);

    // 3) q2,k2 from the fp8-rounded values
    rowreduce8<<<BS / 4, 256, 0, stream>>>(Q8, F, BS, q2);
    rowreduce8<<<BS / 4, 256, 0, stream>>>(K8, F, BS, k2);

    // 4) E; x=batch -> XCD-pinned; (8,16,16) = 2048 blocks (R20, verified)
    gemm128f8<<<dim3(Bz, S / 128, S / 128), 512, 0, stream>>>(
        Q8, F, (long long)S * F,
        K8, F, (long long)S * F,
        E, S, (long long)S * S,
        F, q2, S, k2, S, invs);

    // 5) l = rowsum(E)
    rowreduce<0><<<BS / 4, 256, 0, stream>>>(E, S, BS, lsum);

    // 6) out = (E . V) / l; x=batch -> XCD-pinned; 768 blocks (all-resident)
    gemm128n<2><<<dim3(Bz, F / 128, S / 128), 512, 0, stream>>>(
        E, S, (long long)S * S,
        VT, BS, (long long)S,
        d_out, F, (long long)S * F,
        S, 1, lsum, S);
}

// Round 22
// 247.565 us; speedup vs baseline: 1.0124x; 1.0124x over previous
//
#include <hip/hip_runtime.h>
#include <hip/hip_fp8.h>
#include <stdint.h>
#include <math.h>

// cdist-attention. R22: bf16 trio -> 4-WAVE blocks (de-correlation, m97
// geometry). R21 falsified "more waves": occupancy 24.5->52.8% left PV at
// ~67-69us, MfmaUtil pinned 30% == FLOPs/peak. Cause: 8-wave blocks are
// barrier-locked, so same-block waves on a SIMD stall together. 4-wave
// (256-thread) blocks at 4 blocks/CU put ONE wave from each of 4 independent
// blocks on each SIMD -> stalls de-correlate, MFMA pipe fills.
// gemm4w: BM=BN=128/BK=32, 2x2 waves of 64x64, acc[4][4], LDS 32KB,
// launch_bounds(256,4). Verified swizzle/staging carried over. Scores
// gemm128f8 + rowreduces + casts byte-identical to R20/R21.

typedef __attribute__((ext_vector_type(8))) __bf16 bf16x8;
typedef __attribute__((ext_vector_type(4))) float f32x4;
typedef __attribute__((ext_vector_type(4))) unsigned int u32x4;

__device__ __forceinline__ unsigned short f2b(float f) {
    unsigned u = __float_as_uint(f);
    unsigned r = 0x7fffu + ((u >> 16) & 1u);
    return (unsigned short)((u + r) >> 16);
}
__device__ __forceinline__ float b2f(unsigned short h) {
    return __uint_as_float(((unsigned)h) << 16);
}
__device__ __forceinline__ unsigned char f2f8(float f) {
    __hip_fp8_e4m3 t(f);
    return t.__x;
}
__device__ __forceinline__ float f8tof(unsigned char b) {
    int e = (b >> 3) & 15, m = b & 7;
    float v = e ? ldexpf(8.0f + m, e - 10) : ldexpf((float)m, -9);
    return (b & 0x80) ? -v : v;
}

__device__ __forceinline__ void wg_barrier() {
    asm volatile("" ::: "memory");
    __builtin_amdgcn_s_barrier();
    asm volatile("" ::: "memory");
}

__device__ __forceinline__ unsigned lds_off(const void* p) {
    return (unsigned)(uintptr_t)(const __attribute__((address_space(3))) char*)p;
}

__global__ __launch_bounds__(256) void castk(const float* __restrict__ src,
                                             unsigned short* __restrict__ dst, int n4) {
    int i = blockIdx.x * 256 + threadIdx.x;
    if (i >= n4) return;
    float4 v = ((const float4*)src)[i];
    ushort4 o;
    o.x = f2b(v.x); o.y = f2b(v.y); o.z = f2b(v.z); o.w = f2b(v.w);
    ((ushort4*)dst)[i] = o;
}

// MODE 0: row sum; MODE 1: row sum of squares. One wave per row (bf16 input).
template <int MODE>
__global__ __launch_bounds__(256) void rowreduce(const unsigned short* __restrict__ X,
                                                 int L, int rows, float* __restrict__ out) {
    int w = threadIdx.x >> 6, lane = threadIdx.x & 63;
    int row = blockIdx.x * 4 + w;
    if (row >= rows) return;
    const unsigned short* xr = X + (size_t)row * L;
    float s = 0.f;
    int passes = L >> 8;
    for (int p = 0; p < passes; ++p) {
        ushort4 u = *(const ushort4*)(xr + (p << 8) + lane * 4);
        float a = b2f(u.x), b = b2f(u.y), c = b2f(u.z), d = b2f(u.w);
        s += MODE ? (a * a + b * b + c * c + d * d) : (a + b + c + d);
    }
#pragma unroll
    for (int o = 32; o > 0; o >>= 1) s += __shfl_down(s, o);
    if (lane == 0) out[row] = s;
}

// row sum of squares over fp8-e4m3 rows
__global__ __launch_bounds__(256) void rowreduce8(const unsigned char* __restrict__ X,
                                                  int L, int rows, float* __restrict__ out) {
    int w = threadIdx.x >> 6, lane = threadIdx.x & 63;
    int row = blockIdx.x * 4 + w;
    if (row >= rows) return;
    const unsigned char* xr = X + (size_t)row * L;
    float s = 0.f;
    int passes = L >> 8;
    for (int p = 0; p < passes; ++p) {
        uchar4 u = *(const uchar4*)(xr + (p << 8) + lane * 4);
        float a = f8tof(u.x), b = f8tof(u.y), c = f8tof(u.z), d = f8tof(u.w);
        s += a * a + b * b + c * c + d * d;
    }
#pragma unroll
    for (int o = 32; o > 0; o >>= 1) s += __shfl_down(s, o);
    if (lane == 0) out[row] = s;
}

#define MF(A_, B_, C_) (C_) = __builtin_amdgcn_mfma_f32_16x16x32_bf16((A_), (B_), (C_), 0, 0, 0)
#define MF8(A_, B_, C_) (C_) = __builtin_amdgcn_mfma_f32_16x16x32_fp8_fp8((A_), (B_), (C_), 0, 0, 0)
#define DSR(dst_, a_, imm_) \
    asm volatile("ds_read_b128 %0, %1 offset:" #imm_ : "=v"(dst_) : "v"(a_))
#define DSR64(dst_, a_, imm_) \
    asm volatile("ds_read_b64 %0, %1 offset:" #imm_ : "=v"(dst_) : "v"(a_))
#define GL4(d_, p_) asm volatile("global_load_dwordx4 %0, %1, off" : "=v"(d_) : "v"(p_))
#define DSW(a_, imm_, d_) \
    asm volatile("ds_write_b128 %0, %1 offset:" #imm_ :: "v"(a_), "v"(d_) : "memory")
#define LGKM(n_) asm volatile("s_waitcnt lgkmcnt(" #n_ ")" ::: "memory")
#define VMC0 asm volatile("s_waitcnt vmcnt(0)" ::: "memory")
#define SB0 __builtin_amdgcn_sched_barrier(0)

// ------- bf16 GEMM, 128x128/BK=32, 4 waves (2x2 of 64x64), 4 blocks/CU -------
// Tiles: A/B 128 rows x 64 B (8 KB each, dbuf 32 KB total).
// Staging: thread t stages chunks t (row t>>2) and t+256 (row t>>2 + 64);
//   stored slot t&3, logical chunk clog = (t&3) ^ ((row>>1)&3) (involution
//   verified; +64 rows preserves clog and slot).
// Frag reads: byte = row*64 + ((kq ^ ((c16>>1)&3))<<4); mi/ni -> +1024 imm.
#define LOADT4(T_) do {                                                    \
    const size_t ko_ = (size_t)(T_) * 32;                                  \
    GL4(ra0, pa + ko_); GL4(ra1, pa + lda64 + ko_);                        \
    GL4(rb0, pb + ko_); GL4(rb1, pb + ldb64 + ko_);                        \
} while (0)
#define WRITET4(WB_) do {                                                  \
    DSW(wAa + (WB_), 0, ra0); DSW(wAa + (WB_), 4096, ra1);                 \
    DSW(wBb + (WB_), 0, rb0); DSW(wBb + (WB_), 4096, rb1);                 \
} while (0)

// EPI 0: bf16 out. EPI 2: f32 = acc / aux1[row]. EPI 3: fp8-e4m3 out.
template <int EPI>
__global__ __launch_bounds__(256, 4) void gemm4w(
    const unsigned short* __restrict__ A, int lda, long long sA,
    const unsigned short* __restrict__ B, int ldb, long long sB,
    void* __restrict__ Cv, int ldc, long long sC,
    int Kd, int perm,
    const float* __restrict__ aux1, int sAux1) {
    __shared__ __attribute__((aligned(128))) unsigned short As[2 * 128 * 32];  // 16 KB
    __shared__ __attribute__((aligned(128))) unsigned short Bs[2 * 128 * 32];  // 16 KB

    const int z = perm ? blockIdx.x : blockIdx.z;
    const int jb = perm ? blockIdx.y : blockIdx.x;
    const int ib = perm ? blockIdx.z : blockIdx.y;
    const unsigned short* __restrict__ Ab = A + (size_t)z * sA;
    const unsigned short* __restrict__ Bb = B + (size_t)z * sB;
    const int i0 = ib * 128, j0 = jb * 128;
    const int tid = threadIdx.x;
    const int w = tid >> 6, lane = tid & 63;
    const int wr = w >> 1, wc = w & 1;   // 2M x 2N waves, 64x64 C each
    const int c16 = lane & 15, kq = lane >> 4;

    const int srow = tid >> 2;           // 0..63 (second chunk: +64)
    const int clog = (tid & 3) ^ ((srow >> 1) & 3);
    const unsigned short* pa = Ab + (size_t)(i0 + srow) * lda + clog * 8;
    const unsigned short* pb = Bb + (size_t)(j0 + srow) * ldb + clog * 8;
    const size_t lda64 = (size_t)64 * lda, ldb64 = (size_t)64 * ldb;

    const unsigned wAa = lds_off(As) + (unsigned)tid * 16;
    const unsigned wBb = lds_off(Bs) + (unsigned)tid * 16;

    const int sw = (kq ^ ((c16 >> 1) & 3)) << 4;
    const unsigned adrA0 = lds_off(As) + (unsigned)(wr * 64 + c16) * 64 + sw;
    const unsigned adrB0 = lds_off(Bs) + (unsigned)(wc * 64 + c16) * 64 + sw;

    f32x4 acc[4][4];
    const f32x4 zero = {0.f, 0.f, 0.f, 0.f};
#pragma unroll
    for (int i = 0; i < 4; ++i)
#pragma unroll
        for (int j = 0; j < 4; ++j) acc[i][j] = zero;

    u32x4 ra0, ra1, rb0, rb1;
    bf16x8 aF[4], bF[4];

    const int nt = Kd >> 5;  // BK=32 tiles

    LOADT4(0);
    VMC0;
    WRITET4(0u);
    LOADT4(1);
    LGKM(0);
    wg_barrier();

    for (int t = 0; t < nt; ++t) {
        const unsigned rb_ = (t & 1) ? 8192u : 0u;
        const unsigned wb_ = (t & 1) ? 0u : 8192u;
        const unsigned aA = adrA0 + rb_;
        const unsigned aB = adrB0 + rb_;
        DSR(aF[0], aA, 0);    DSR(aF[1], aA, 1024);
        DSR(aF[2], aA, 2048); DSR(aF[3], aA, 3072);
        DSR(bF[0], aB, 0);    DSR(bF[1], aB, 1024);
        DSR(bF[2], aB, 2048); DSR(bF[3], aB, 3072);
        if (t + 1 < nt) {
            VMC0;            // loads for t+1 issued one tile ago
            WRITET4(wb_);
            if (t + 2 < nt) LOADT4(t + 2);
            LGKM(4);         // 8 reads done; 4 writes may remain
        } else {
            LGKM(0);
        }
        SB0;
        __builtin_amdgcn_s_setprio(1);
#pragma unroll
        for (int mi = 0; mi < 4; ++mi)
#pragma unroll
            for (int ni = 0; ni < 4; ++ni)
                MF(aF[mi], bF[ni], acc[mi][ni]);
        __builtin_amdgcn_s_setprio(0);
        LGKM(0);             // publish writes before barrier
        wg_barrier();
    }

    const int prow = kq * 4;
    if constexpr (EPI == 0) {
        unsigned short* C = (unsigned short*)Cv + (size_t)z * sC;
#pragma unroll
        for (int mi = 0; mi < 4; ++mi)
#pragma unroll
            for (int ni = 0; ni < 4; ++ni) {
                const int row = i0 + wr * 64 + mi * 16 + prow;
                const int col = j0 + wc * 64 + ni * 16 + c16;
#pragma unroll
                for (int r = 0; r < 4; ++r)
                    C[(size_t)(row + r) * ldc + col] = f2b(acc[mi][ni][r]);
            }
    } else if constexpr (EPI == 3) {
        unsigned char* C = (unsigned char*)Cv + (size_t)z * sC;
#pragma unroll
        for (int mi = 0; mi < 4; ++mi)
#pragma unroll
            for (int ni = 0; ni < 4; ++ni) {
                const int row = i0 + wr * 64 + mi * 16 + prow;
                const int col = j0 + wc * 64 + ni * 16 + c16;
#pragma unroll
                for (int r = 0; r < 4; ++r)
                    C[(size_t)(row + r) * ldc + col] = f2f8(acc[mi][ni][r]);
            }
    } else {
        float* C = (float*)Cv + (size_t)z * sC;
        const float* lb = aux1 + (size_t)z * sAux1;
#pragma unroll
        for (int mi = 0; mi < 4; ++mi) {
            const int row = i0 + wr * 64 + mi * 16 + prow;
            float linv[4];
#pragma unroll
            for (int r = 0; r < 4; ++r) linv[r] = 1.0f / lb[row + r];
#pragma unroll
            for (int ni = 0; ni < 4; ++ni) {
                const int col = j0 + wc * 64 + ni * 16 + c16;
#pragma unroll
                for (int r = 0; r < 4; ++r)
                    C[(size_t)(row + r) * ldc + col] = acc[mi][ni][r] * linv[r];
            }
        }
    }
}

// -------- fp8 scores GEMM (R20, verified): BM=128 x BN=128, 3 blocks/CU --------
#define LOADT8(T_) do {                                                    \
    const size_t ko_ = (size_t)(T_) * 64;                                  \
    GL4(fa0, pa8 + ko_);                                                   \
    GL4(fb0, pb8 + ko_);                                                   \
} while (0)
#define WRITET8(WB_) do {                                                  \
    DSW(wA8 + (WB_), 0, fa0);                                              \
    DSW(wB8 + (WB_), 0, fb0);                                              \
} while (0)

__global__ __launch_bounds__(512, 6) void gemm128f8(
    const unsigned char* __restrict__ A, int lda, long long sA,
    const unsigned char* __restrict__ B, int ldb, long long sB,
    unsigned short* __restrict__ Cq, int ldc, long long sC,
    int Kd,
    const float* __restrict__ q2a, int sQ2,
    const float* __restrict__ k2a, int sK2,
    float invs) {
    __shared__ __attribute__((aligned(128))) unsigned char As8[2 * 128 * 64];  // 16 KB
    __shared__ __attribute__((aligned(128))) unsigned char Bs8[2 * 128 * 64];  // 16 KB

    const int z = blockIdx.x;        // XCD i owns batch i
    const int jb = blockIdx.y, ib = blockIdx.z;
    const unsigned char* __restrict__ Ab = A + (size_t)z * sA;
    const unsigned char* __restrict__ Bb = B + (size_t)z * sB;
    const int i0 = ib * 128, j0 = jb * 128;
    const int tid = threadIdx.x;
    const int w = tid >> 6, lane = tid & 63;
    const int wr = w >> 2, wc = w & 3;   // 2M x 4N waves, 64x32 C each
    const int c16 = lane & 15, kq = lane >> 4;

    const int srow = tid >> 2;           // 0..127
    const int p8 = (tid & 3) ^ (srow & 3) ^ ((srow >> 2) & 1);
    const unsigned char* pa8 = Ab + (size_t)(i0 + srow) * lda + p8 * 16;
    const unsigned char* pb8 = Bb + (size_t)(j0 + srow) * ldb + p8 * 16;

    const unsigned wA8 = lds_off(As8) + (unsigned)tid * 16;
    const unsigned wB8 = lds_off(Bs8) + (unsigned)tid * 16;

    const int gl = (c16 & 3) ^ ((c16 >> 2) & 1);
    const int soff = ((((kq >> 1) ^ gl) << 4) | ((kq & 1) << 3));
    const unsigned adrA80 = lds_off(As8) + (unsigned)(wr * 64 + c16) * 64 + soff;
    const unsigned adrB80 = lds_off(Bs8) + (unsigned)(wc * 32 + c16) * 64 + soff;

    f32x4 acc[4][2];
    const f32x4 zero = {0.f, 0.f, 0.f, 0.f};
#pragma unroll
    for (int i = 0; i < 4; ++i)
#pragma unroll
        for (int j = 0; j < 2; ++j) acc[i][j] = zero;

    u32x4 fa0, fb0;
    long aF[4][2], bF[2][2];

    const int nt = Kd >> 6;  // 12

    LOADT8(0);
    VMC0;
    WRITET8(0u);
    LOADT8(1);
    LGKM(0);
    wg_barrier();

    for (int t = 0; t < nt; ++t) {
        const unsigned rb_ = (t & 1) ? 8192u : 0u;
        const unsigned wb_ = (t & 1) ? 0u : 8192u;
        const unsigned aA = adrA80 + rb_, aAx = aA ^ 32u;
        const unsigned aB = adrB80 + rb_, aBx = aB ^ 32u;
        DSR64(aF[0][0], aA, 0);    DSR64(aF[0][1], aAx, 0);
        DSR64(aF[1][0], aA, 1024); DSR64(aF[1][1], aAx, 1024);
        DSR64(aF[2][0], aA, 2048); DSR64(aF[2][1], aAx, 2048);
        DSR64(aF[3][0], aA, 3072); DSR64(aF[3][1], aAx, 3072);
        DSR64(bF[0][0], aB, 0);    DSR64(bF[0][1], aBx, 0);
        DSR64(bF[1][0], aB, 1024); DSR64(bF[1][1], aBx, 1024);
        if (t + 1 < nt) {
            VMC0;
            WRITET8(wb_);
            if (t + 2 < nt) LOADT8(t + 2);
            LGKM(2);
        } else {
            LGKM(0);
        }
        SB0;
        __builtin_amdgcn_s_setprio(1);
#pragma unroll
        for (int kk = 0; kk < 2; ++kk)
#pragma unroll
            for (int mi = 0; mi < 4; ++mi)
#pragma unroll
                for (int ni = 0; ni < 2; ++ni)
                    MF8(aF[mi][kk], bF[ni][kk], acc[mi][ni]);
        __builtin_amdgcn_s_setprio(0);
        LGKM(0);
        wg_barrier();
    }

    // scores epilogue: E -> bf16 via per-wave transpose (16x40 shorts in dead As8)
    unsigned short* C = Cq + (size_t)z * sC;
    const float* q2b = q2a + (size_t)z * sQ2;
    const float* k2b = k2a + (size_t)z * sK2;
    unsigned short* sc = (unsigned short*)(As8 + w * 2048);
    const int prow = kq * 4;
    const int rr = lane >> 2, ch = lane & 3;
#pragma unroll
    for (int mi = 0; mi < 4; ++mi) {
#pragma unroll
        for (int ni = 0; ni < 2; ++ni) {
            const int col = j0 + wc * 32 + ni * 16 + c16;
            const float k2v = k2b[col];
#pragma unroll
            for (int r = 0; r < 4; ++r) {
                const int grow = i0 + wr * 64 + mi * 16 + prow + r;
                float d2 = q2b[grow] + k2v - 2.0f * acc[mi][ni][r];
                float e = __expf(sqrtf(fmaxf(d2, 0.f)) * invs);
                sc[(prow + r) * 40 + ni * 16 + c16] = f2b(e);
            }
        }
        bf16x8 v = *(const bf16x8*)&sc[rr * 40 + ch * 8];
        const int grow = i0 + wr * 64 + mi * 16 + rr;
        *(bf16x8*)&C[(size_t)grow * ldc + j0 + wc * 32 + ch * 8] = v;
    }
}

extern "C" void kernel_launch(void* const* d_in, const int* in_sizes, int n_in,
                              void* d_out, int out_size, void* d_ws, size_t ws_size,
                              hipStream_t stream) {
    const float* x = (const float*)d_in[0];
    const float* Wq = (const float*)d_in[1];
    const float* Wk = (const float*)d_in[2];
    const float* Wv = (const float*)d_in[3];
    const int Bz = 8, S = 2048, D = 768, F = 768;
    const int BS = Bz * S;  // 16384

    const size_t szX = (size_t)BS * D * 2;
    const size_t szW = (size_t)F * D * 2;
    const size_t szQ8 = (size_t)BS * F;
    const size_t szE = (size_t)Bz * S * S * 2;

    char* p = (char*)d_ws;
    unsigned short* xb = (unsigned short*)p;  p += szX;
    unsigned short* Wqb = (unsigned short*)p; p += szW;
    unsigned short* Wkb = (unsigned short*)p; p += szW;
    unsigned short* Wvb = (unsigned short*)p; p += szW;
    unsigned char* Q8 = (unsigned char*)p;    p += szQ8;
    unsigned char* K8 = (unsigned char*)p;    p += szQ8;
    unsigned short* VT = (unsigned short*)p;  p += szX;   // [F][BS]
    unsigned short* E = (unsigned short*)p;   p += szE;   // [Bz][S][S]
    float* q2 = (float*)p;    p += (size_t)BS * 4;
    float* k2 = (float*)p;    p += (size_t)BS * 4;
    float* lsum = (float*)p;  p += (size_t)BS * 4;
    if ((size_t)(p - (char*)d_ws) > ws_size) return;  // ~147 MiB scratch required

    const float invs = 1.0f / sqrtf(768.0f);

    // 1) casts
    castk<<<(BS * D / 4 + 255) / 256, 256, 0, stream>>>(x, xb, BS * D / 4);
    castk<<<(F * D / 4 + 255) / 256, 256, 0, stream>>>(Wq, Wqb, F * D / 4);
    castk<<<(F * D / 4 + 255) / 256, 256, 0, stream>>>(Wk, Wkb, F * D / 4);
    castk<<<(F * D / 4 + 255) / 256, 256, 0, stream>>>(Wv, Wvb, F * D / 4);

    // 2) Q8,K8 = e4m3(x . W^T)  (z=0 -> Wq->Q8, z=1 -> Wk->K8); 1536 blocks
    gemm4w<3><<<dim3(F / 128, BS / 128, 2), 256, 0, stream>>>(
        xb, D, 0,
        Wqb, D, (long long)F * D,
        Q8, F, (long long)BS * F,
        D, 0, nullptr, 0);

    //    V^T = Wv . x^T -> VT[f][s] (bf16); 768 blocks
    gemm4w<0><<<dim3(BS / 128, F / 128, 1), 256, 0, stream>>>(
        Wvb, D, 0,
        xb, D, 0,
        VT, BS, 0,
        D, 0, nullptr, 0);

    // 3) q2,k2 from the fp8-rounded values
    rowreduce8<<<BS / 4, 256, 0, stream>>>(Q8, F, BS, q2);
    rowreduce8<<<BS / 4, 256, 0, stream>>>(K8, F, BS, k2);

    // 4) E; x=batch -> XCD-pinned; (8,16,16) = 2048 blocks (R20, verified)
    gemm128f8<<<dim3(Bz, S / 128, S / 128), 512, 0, stream>>>(
        Q8, F, (long long)S * F,
        K8, F, (long long)S * F,
        E, S, (long long)S * S,
        F, q2, S, k2, S, invs);

    // 5) l = rowsum(E)
    rowreduce<0><<<BS / 4, 256, 0, stream>>>(E, S, BS, lsum);

    // 6) out = (E . V) / l; x=batch -> XCD-pinned; 768 blocks
    gemm4w<2><<<dim3(Bz, F / 128, S / 128), 256, 0, stream>>>(
        E, S, (long long)S * S,
        VT, BS, (long long)S,
        d_out, F, (long long)S * F,
        S, 1, lsum, S);
}

// Round 24
// 235.164 us; speedup vs baseline: 1.0658x; 1.0527x over previous
//
#include <hip/hip_runtime.h>
#include <hip/hip_fp8.h>
#include <stdint.h>
#include <math.h>

// cdist-attention. R24 = R20 verbatim (best verified: 234.8us; R18/R19/R20
// all 233-235 = plateau). R23's depth-2 graft aborted at runtime: +24 stage
// VGPRs under launch_bounds(512,4)'s 128-reg budget forces spills of
// in-flight inline-asm global_load destinations (R13's depth-2 ran at 256
// regs). Banking the proven build: scores gemm128f8 @3 blocks/CU (<=66us),
// bf16 trio gemm128b @2 blocks/CU (67-70us), rowreduce lsum, XCD pinning.

typedef __attribute__((ext_vector_type(8))) __bf16 bf16x8;
typedef __attribute__((ext_vector_type(4))) float f32x4;
typedef __attribute__((ext_vector_type(4))) unsigned int u32x4;

__device__ __forceinline__ unsigned short f2b(float f) {
    unsigned u = __float_as_uint(f);
    unsigned r = 0x7fffu + ((u >> 16) & 1u);
    return (unsigned short)((u + r) >> 16);
}
__device__ __forceinline__ float b2f(unsigned short h) {
    return __uint_as_float(((unsigned)h) << 16);
}
__device__ __forceinline__ unsigned char f2f8(float f) {
    __hip_fp8_e4m3 t(f);
    return t.__x;
}
__device__ __forceinline__ float f8tof(unsigned char b) {
    int e = (b >> 3) & 15, m = b & 7;
    float v = e ? ldexpf(8.0f + m, e - 10) : ldexpf((float)m, -9);
    return (b & 0x80) ? -v : v;
}

__device__ __forceinline__ void wg_barrier() {
    asm volatile("" ::: "memory");
    __builtin_amdgcn_s_barrier();
    asm volatile("" ::: "memory");
}

__device__ __forceinline__ unsigned lds_off(const void* p) {
    return (unsigned)(uintptr_t)(const __attribute__((address_space(3))) char*)p;
}

__global__ __launch_bounds__(256) void castk(const float* __restrict__ src,
                                             unsigned short* __restrict__ dst, int n4) {
    int i = blockIdx.x * 256 + threadIdx.x;
    if (i >= n4) return;
    float4 v = ((const float4*)src)[i];
    ushort4 o;
    o.x = f2b(v.x); o.y = f2b(v.y); o.z = f2b(v.z); o.w = f2b(v.w);
    ((ushort4*)dst)[i] = o;
}

// MODE 0: row sum; MODE 1: row sum of squares. One wave per row (bf16 input).
template <int MODE>
__global__ __launch_bounds__(256) void rowreduce(const unsigned short* __restrict__ X,
                                                 int L, int rows, float* __restrict__ out) {
    int w = threadIdx.x >> 6, lane = threadIdx.x & 63;
    int row = blockIdx.x * 4 + w;
    if (row >= rows) return;
    const unsigned short* xr = X + (size_t)row * L;
    float s = 0.f;
    int passes = L >> 8;
    for (int p = 0; p < passes; ++p) {
        ushort4 u = *(const ushort4*)(xr + (p << 8) + lane * 4);
        float a = b2f(u.x), b = b2f(u.y), c = b2f(u.z), d = b2f(u.w);
        s += MODE ? (a * a + b * b + c * c + d * d) : (a + b + c + d);
    }
#pragma unroll
    for (int o = 32; o > 0; o >>= 1) s += __shfl_down(s, o);
    if (lane == 0) out[row] = s;
}

// row sum of squares over fp8-e4m3 rows
__global__ __launch_bounds__(256) void rowreduce8(const unsigned char* __restrict__ X,
                                                  int L, int rows, float* __restrict__ out) {
    int w = threadIdx.x >> 6, lane = threadIdx.x & 63;
    int row = blockIdx.x * 4 + w;
    if (row >= rows) return;
    const unsigned char* xr = X + (size_t)row * L;
    float s = 0.f;
    int passes = L >> 8;
    for (int p = 0; p < passes; ++p) {
        uchar4 u = *(const uchar4*)(xr + (p << 8) + lane * 4);
        float a = f8tof(u.x), b = f8tof(u.y), c = f8tof(u.z), d = f8tof(u.w);
        s += a * a + b * b + c * c + d * d;
    }
#pragma unroll
    for (int o = 32; o > 0; o >>= 1) s += __shfl_down(s, o);
    if (lane == 0) out[row] = s;
}

#define MF(A_, B_, C_) (C_) = __builtin_amdgcn_mfma_f32_16x16x32_bf16((A_), (B_), (C_), 0, 0, 0)
#define MF8(A_, B_, C_) (C_) = __builtin_amdgcn_mfma_f32_16x16x32_fp8_fp8((A_), (B_), (C_), 0, 0, 0)
#define DSR(dst_, a_, imm_) \
    asm volatile("ds_read_b128 %0, %1 offset:" #imm_ : "=v"(dst_) : "v"(a_))
#define DSR64(dst_, a_, imm_) \
    asm volatile("ds_read_b64 %0, %1 offset:" #imm_ : "=v"(dst_) : "v"(a_))
#define GL4(d_, p_) asm volatile("global_load_dwordx4 %0, %1, off" : "=v"(d_) : "v"(p_))
#define DSW(a_, imm_, d_) \
    asm volatile("ds_write_b128 %0, %1 offset:" #imm_ :: "v"(a_), "v"(d_) : "memory")
#define LGKM(n_) asm volatile("s_waitcnt lgkmcnt(" #n_ ")" ::: "memory")
#define VMC0 asm volatile("s_waitcnt vmcnt(0)" ::: "memory")
#define SB0 __builtin_amdgcn_sched_barrier(0)

// ---------------- bf16 GEMM, 128x256/BK=32, 2 blocks/CU ----------------
#define LOADTB(T_) do {                                                    \
    const size_t ko_ = (size_t)(T_) * 32;                                  \
    GL4(ra0, pa + ko_);                                                    \
    GL4(rb0, pb + ko_); GL4(rb1, pb + ldb128 + ko_);                       \
} while (0)
#define WRITETB(WB_) do {                                                  \
    DSW(wAa + ((WB_) >> 1), 0, ra0);                                       \
    DSW(wBb + (WB_), 0, rb0); DSW(wBb + (WB_), 8192, rb1);                 \
} while (0)

// EPI 0: bf16 out. EPI 2: f32 = acc / aux1[row]. EPI 3: fp8-e4m3 out.
template <int EPI>
__global__ __launch_bounds__(512, 4) void gemm128b(
    const unsigned short* __restrict__ A, int lda, long long sA,
    const unsigned short* __restrict__ B, int ldb, long long sB,
    void* __restrict__ Cv, int ldc, long long sC,
    int Kd, int perm,
    const float* __restrict__ aux1, int sAux1) {
    __shared__ __attribute__((aligned(128))) unsigned short As[2 * 128 * 32];  // 16 KB
    __shared__ __attribute__((aligned(128))) unsigned short Bs[2 * 256 * 32];  // 32 KB

    const int z = perm ? blockIdx.x : blockIdx.z;
    const int jb = perm ? blockIdx.y : blockIdx.x;
    const int ib = perm ? blockIdx.z : blockIdx.y;
    const unsigned short* __restrict__ Ab = A + (size_t)z * sA;
    const unsigned short* __restrict__ Bb = B + (size_t)z * sB;
    const int i0 = ib * 128, j0 = jb * 256;
    const int tid = threadIdx.x;
    const int w = tid >> 6, lane = tid & 63;
    const int wr = w >> 2, wc = w & 3;   // 2M x 4N waves, 64x64 C each
    const int c16 = lane & 15, kq = lane >> 4;

    const int srow = tid >> 2;
    const int clog = (tid & 3) ^ ((srow >> 1) & 3);
    const unsigned short* pa = Ab + (size_t)(i0 + srow) * lda + clog * 8;
    const unsigned short* pb = Bb + (size_t)(j0 + srow) * ldb + clog * 8;
    const size_t ldb128 = (size_t)128 * ldb;

    const unsigned wAa = lds_off(As) + (unsigned)tid * 16;
    const unsigned wBb = lds_off(Bs) + (unsigned)tid * 16;

    const int sw = (kq ^ ((c16 >> 1) & 3)) << 4;
    const unsigned adrA0 = lds_off(As) + (unsigned)(wr * 64 + c16) * 64 + sw;
    const unsigned adrB0 = lds_off(Bs) + (unsigned)(wc * 64 + c16) * 64 + sw;

    f32x4 acc[4][4];
    const f32x4 zero = {0.f, 0.f, 0.f, 0.f};
#pragma unroll
    for (int i = 0; i < 4; ++i)
#pragma unroll
        for (int j = 0; j < 4; ++j) acc[i][j] = zero;

    u32x4 ra0, rb0, rb1;
    bf16x8 aF[4], bF[4];

    const int nt = Kd >> 5;

    LOADTB(0);
    VMC0;
    WRITETB(0u);
    LOADTB(1);
    LGKM(0);
    wg_barrier();

    for (int t = 0; t < nt; ++t) {
        const unsigned rb_ = (t & 1) ? 16384u : 0u;
        const unsigned wb_ = (t & 1) ? 0u : 16384u;
        const unsigned aA = adrA0 + (rb_ >> 1);
        const unsigned aB = adrB0 + rb_;
        DSR(aF[0], aA, 0);    DSR(aF[1], aA, 1024);
        DSR(aF[2], aA, 2048); DSR(aF[3], aA, 3072);
        DSR(bF[0], aB, 0);    DSR(bF[1], aB, 1024);
        DSR(bF[2], aB, 2048); DSR(bF[3], aB, 3072);
        if (t + 1 < nt) {
            VMC0;
            WRITETB(wb_);
            if (t + 2 < nt) LOADTB(t + 2);
            LGKM(3);
        } else {
            LGKM(0);
        }
        SB0;
        __builtin_amdgcn_s_setprio(1);
#pragma unroll
        for (int mi = 0; mi < 4; ++mi)
#pragma unroll
            for (int ni = 0; ni < 4; ++ni)
                MF(aF[mi], bF[ni], acc[mi][ni]);
        __builtin_amdgcn_s_setprio(0);
        LGKM(0);
        wg_barrier();
    }

    const int prow = kq * 4;
    if constexpr (EPI == 0) {
        unsigned short* C = (unsigned short*)Cv + (size_t)z * sC;
#pragma unroll
        for (int mi = 0; mi < 4; ++mi)
#pragma unroll
            for (int ni = 0; ni < 4; ++ni) {
                const int row = i0 + wr * 64 + mi * 16 + prow;
                const int col = j0 + wc * 64 + ni * 16 + c16;
#pragma unroll
                for (int r = 0; r < 4; ++r)
                    C[(size_t)(row + r) * ldc + col] = f2b(acc[mi][ni][r]);
            }
    } else if constexpr (EPI == 3) {
        unsigned char* C = (unsigned char*)Cv + (size_t)z * sC;
#pragma unroll
        for (int mi = 0; mi < 4; ++mi)
#pragma unroll
            for (int ni = 0; ni < 4; ++ni) {
                const int row = i0 + wr * 64 + mi * 16 + prow;
                const int col = j0 + wc * 64 + ni * 16 + c16;
#pragma unroll
                for (int r = 0; r < 4; ++r)
                    C[(size_t)(row + r) * ldc + col] = f2f8(acc[mi][ni][r]);
            }
    } else {
        float* C = (float*)Cv + (size_t)z * sC;
        const float* lb = aux1 + (size_t)z * sAux1;
#pragma unroll
        for (int mi = 0; mi < 4; ++mi) {
            const int row = i0 + wr * 64 + mi * 16 + prow;
            float linv[4];
#pragma unroll
            for (int r = 0; r < 4; ++r) linv[r] = 1.0f / lb[row + r];
#pragma unroll
            for (int ni = 0; ni < 4; ++ni) {
                const int col = j0 + wc * 64 + ni * 16 + c16;
#pragma unroll
                for (int r = 0; r < 4; ++r)
                    C[(size_t)(row + r) * ldc + col] = acc[mi][ni][r] * linv[r];
            }
        }
    }
}

// -------- fp8 scores GEMM: BM=128 x BN=128, acc[4][2], 3 blocks/CU --------
#define LOADT8(T_) do {                                                    \
    const size_t ko_ = (size_t)(T_) * 64;                                  \
    GL4(fa0, pa8 + ko_);                                                   \
    GL4(fb0, pb8 + ko_);                                                   \
} while (0)
#define WRITET8(WB_) do {                                                  \
    DSW(wA8 + (WB_), 0, fa0);                                              \
    DSW(wB8 + (WB_), 0, fb0);                                              \
} while (0)

__global__ __launch_bounds__(512, 6) void gemm128f8(
    const unsigned char* __restrict__ A, int lda, long long sA,
    const unsigned char* __restrict__ B, int ldb, long long sB,
    unsigned short* __restrict__ Cq, int ldc, long long sC,
    int Kd,
    const float* __restrict__ q2a, int sQ2,
    const float* __restrict__ k2a, int sK2,
    float invs) {
    __shared__ __attribute__((aligned(128))) unsigned char As8[2 * 128 * 64];  // 16 KB
    __shared__ __attribute__((aligned(128))) unsigned char Bs8[2 * 128 * 64];  // 16 KB

    const int z = blockIdx.x;        // XCD i owns batch i
    const int jb = blockIdx.y, ib = blockIdx.z;
    const unsigned char* __restrict__ Ab = A + (size_t)z * sA;
    const unsigned char* __restrict__ Bb = B + (size_t)z * sB;
    const int i0 = ib * 128, j0 = jb * 128;
    const int tid = threadIdx.x;
    const int w = tid >> 6, lane = tid & 63;
    const int wr = w >> 2, wc = w & 3;   // 2M x 4N waves, 64x32 C each
    const int c16 = lane & 15, kq = lane >> 4;

    const int srow = tid >> 2;           // 0..127
    const int p8 = (tid & 3) ^ (srow & 3) ^ ((srow >> 2) & 1);
    const unsigned char* pa8 = Ab + (size_t)(i0 + srow) * lda + p8 * 16;
    const unsigned char* pb8 = Bb + (size_t)(j0 + srow) * ldb + p8 * 16;

    const unsigned wA8 = lds_off(As8) + (unsigned)tid * 16;
    const unsigned wB8 = lds_off(Bs8) + (unsigned)tid * 16;

    const int gl = (c16 & 3) ^ ((c16 >> 2) & 1);
    const int soff = ((((kq >> 1) ^ gl) << 4) | ((kq & 1) << 3));
    const unsigned adrA80 = lds_off(As8) + (unsigned)(wr * 64 + c16) * 64 + soff;
    const unsigned adrB80 = lds_off(Bs8) + (unsigned)(wc * 32 + c16) * 64 + soff;

    f32x4 acc[4][2];
    const f32x4 zero = {0.f, 0.f, 0.f, 0.f};
#pragma unroll
    for (int i = 0; i < 4; ++i)
#pragma unroll
        for (int j = 0; j < 2; ++j) acc[i][j] = zero;

    u32x4 fa0, fb0;
    long aF[4][2], bF[2][2];

    const int nt = Kd >> 6;  // 12

    LOADT8(0);
    VMC0;
    WRITET8(0u);
    LOADT8(1);
    LGKM(0);
    wg_barrier();

    for (int t = 0; t < nt; ++t) {
        const unsigned rb_ = (t & 1) ? 8192u : 0u;
        const unsigned wb_ = (t & 1) ? 0u : 8192u;
        const unsigned aA = adrA80 + rb_, aAx = aA ^ 32u;
        const unsigned aB = adrB80 + rb_, aBx = aB ^ 32u;
        DSR64(aF[0][0], aA, 0);    DSR64(aF[0][1], aAx, 0);
        DSR64(aF[1][0], aA, 1024); DSR64(aF[1][1], aAx, 1024);
        DSR64(aF[2][0], aA, 2048); DSR64(aF[2][1], aAx, 2048);
        DSR64(aF[3][0], aA, 3072); DSR64(aF[3][1], aAx, 3072);
        DSR64(bF[0][0], aB, 0);    DSR64(bF[0][1], aBx, 0);
        DSR64(bF[1][0], aB, 1024); DSR64(bF[1][1], aBx, 1024);
        if (t + 1 < nt) {
            VMC0;
            WRITET8(wb_);
            if (t + 2 < nt) LOADT8(t + 2);
            LGKM(2);
        } else {
            LGKM(0);
        }
        SB0;
        __builtin_amdgcn_s_setprio(1);
#pragma unroll
        for (int kk = 0; kk < 2; ++kk)
#pragma unroll
            for (int mi = 0; mi < 4; ++mi)
#pragma unroll
                for (int ni = 0; ni < 2; ++ni)
                    MF8(aF[mi][kk], bF[ni][kk], acc[mi][ni]);
        __builtin_amdgcn_s_setprio(0);
        LGKM(0);
        wg_barrier();
    }

    // scores epilogue: E -> bf16 via per-wave transpose (16x40 shorts in dead As8)
    unsigned short* C = Cq + (size_t)z * sC;
    const float* q2b = q2a + (size_t)z * sQ2;
    const float* k2b = k2a + (size_t)z * sK2;
    unsigned short* sc = (unsigned short*)(As8 + w * 2048);
    const int prow = kq * 4;
    const int rr = lane >> 2, ch = lane & 3;
#pragma unroll
    for (int mi = 0; mi < 4; ++mi) {
#pragma unroll
        for (int ni = 0; ni < 2; ++ni) {
            const int col = j0 + wc * 32 + ni * 16 + c16;
            const float k2v = k2b[col];
#pragma unroll
            for (int r = 0; r < 4; ++r) {
                const int grow = i0 + wr * 64 + mi * 16 + prow + r;
                float d2 = q2b[grow] + k2v - 2.0f * acc[mi][ni][r];
                float e = __expf(sqrtf(fmaxf(d2, 0.f)) * invs);
                sc[(prow + r) * 40 + ni * 16 + c16] = f2b(e);
            }
        }
        bf16x8 v = *(const bf16x8*)&sc[rr * 40 + ch * 8];
        const int grow = i0 + wr * 64 + mi * 16 + rr;
        *(bf16x8*)&C[(size_t)grow * ldc + j0 + wc * 32 + ch * 8] = v;
    }
}

extern "C" void kernel_launch(void* const* d_in, const int* in_sizes, int n_in,
                              void* d_out, int out_size, void* d_ws, size_t ws_size,
                              hipStream_t stream) {
    const float* x = (const float*)d_in[0];
    const float* Wq = (const float*)d_in[1];
    const float* Wk = (const float*)d_in[2];
    const float* Wv = (const float*)d_in[3];
    const int Bz = 8, S = 2048, D = 768, F = 768;
    const int BS = Bz * S;  // 16384

    const size_t szX = (size_t)BS * D * 2;
    const size_t szW = (size_t)F * D * 2;
    const size_t szQ8 = (size_t)BS * F;
    const size_t szE = (size_t)Bz * S * S * 2;

    char* p = (char*)d_ws;
    unsigned short* xb = (unsigned short*)p;  p += szX;
    unsigned short* Wqb = (unsigned short*)p; p += szW;
    unsigned short* Wkb = (unsigned short*)p; p += szW;
    unsigned short* Wvb = (unsigned short*)p; p += szW;
    unsigned char* Q8 = (unsigned char*)p;    p += szQ8;
    unsigned char* K8 = (unsigned char*)p;    p += szQ8;
    unsigned short* VT = (unsigned short*)p;  p += szX;   // [F][BS]
    unsigned short* E = (unsigned short*)p;   p += szE;   // [Bz][S][S]
    float* q2 = (float*)p;    p += (size_t)BS * 4;
    float* k2 = (float*)p;    p += (size_t)BS * 4;
    float* lsum = (float*)p;  p += (size_t)BS * 4;
    if ((size_t)(p - (char*)d_ws) > ws_size) return;  // ~147 MiB scratch required

    const float invs = 1.0f / sqrtf(768.0f);

    // 1) casts
    castk<<<(BS * D / 4 + 255) / 256, 256, 0, stream>>>(x, xb, BS * D / 4);
    castk<<<(F * D / 4 + 255) / 256, 256, 0, stream>>>(Wq, Wqb, F * D / 4);
    castk<<<(F * D / 4 + 255) / 256, 256, 0, stream>>>(Wk, Wkb, F * D / 4);
    castk<<<(F * D / 4 + 255) / 256, 256, 0, stream>>>(Wv, Wvb, F * D / 4);

    // 2) Q8,K8 = e4m3(x . W^T)  (z=0 -> Wq->Q8, z=1 -> Wk->K8); 768 blocks
    gemm128b<3><<<dim3(F / 256, BS / 128, 2), 512, 0, stream>>>(
        xb, D, 0,
        Wqb, D, (long long)F * D,
        Q8, F, (long long)BS * F,
        D, 0, nullptr, 0);

    //    V^T = Wv . x^T -> VT[f][s] (bf16); 384 blocks
    gemm128b<0><<<dim3(BS / 256, F / 128, 1), 512, 0, stream>>>(
        Wvb, D, 0,
        xb, D, 0,
        VT, BS, 0,
        D, 0, nullptr, 0);

    // 3) q2,k2 from the fp8-rounded values
    rowreduce8<<<BS / 4, 256, 0, stream>>>(Q8, F, BS, q2);
    rowreduce8<<<BS / 4, 256, 0, stream>>>(K8, F, BS, k2);

    // 4) E; x=batch -> XCD-pinned; (8,16,16) = 2048 blocks
    gemm128f8<<<dim3(Bz, S / 128, S / 128), 512, 0, stream>>>(
        Q8, F, (long long)S * F,
        K8, F, (long long)S * F,
        E, S, (long long)S * S,
        F, q2, S, k2, S, invs);

    // 5) l = rowsum(E)
    rowreduce<0><<<BS / 4, 256, 0, stream>>>(E, S, BS, lsum);

    // 6) out = (E . V) / l; x=batch -> XCD-pinned; 384 blocks
    gemm128b<2><<<dim3(Bz, F / 256, S / 128), 512, 0, stream>>>(
        E, S, (long long)S * S,
        VT, BS, (long long)S,
        d_out, F, (long long)S * F,
        S, 1, lsum, S);
}

// Round 25
// 233.601 us; speedup vs baseline: 1.0729x; 1.0067x over previous
//
#include <hip/hip_runtime.h>
#include <hip/hip_fp8.h>
#include <stdint.h>
#include <math.h>

// cdist-attention. R25 = R24/R20 (verified 233-235us plateau) + dispatch
// consolidation: Q8/K8 contiguous and q2/k2 contiguous in ws -> the two
// rowreduce8 dispatches merge into one over 2*BS rows (pure pointer
// arithmetic, kernel unchanged). Terminal build: every GEMM sits at the
// learn-loop-documented 2-phase-structure ceiling (m233: 607TF full-2ph vs
// 2145 MFMA-only); 8-phase escapes measured null in this regime (R2/R4
// short-K; m232 128x128 quadrant).

typedef __attribute__((ext_vector_type(8))) __bf16 bf16x8;
typedef __attribute__((ext_vector_type(4))) float f32x4;
typedef __attribute__((ext_vector_type(4))) unsigned int u32x4;

__device__ __forceinline__ unsigned short f2b(float f) {
    unsigned u = __float_as_uint(f);
    unsigned r = 0x7fffu + ((u >> 16) & 1u);
    return (unsigned short)((u + r) >> 16);
}
__device__ __forceinline__ float b2f(unsigned short h) {
    return __uint_as_float(((unsigned)h) << 16);
}
__device__ __forceinline__ unsigned char f2f8(float f) {
    __hip_fp8_e4m3 t(f);
    return t.__x;
}
__device__ __forceinline__ float f8tof(unsigned char b) {
    int e = (b >> 3) & 15, m = b & 7;
    float v = e ? ldexpf(8.0f + m, e - 10) : ldexpf((float)m, -9);
    return (b & 0x80) ? -v : v;
}

__device__ __forceinline__ void wg_barrier() {
    asm volatile("" ::: "memory");
    __builtin_amdgcn_s_barrier();
    asm volatile("" ::: "memory");
}

__device__ __forceinline__ unsigned lds_off(const void* p) {
    return (unsigned)(uintptr_t)(const __attribute__((address_space(3))) char*)p;
}

__global__ __launch_bounds__(256) void castk(const float* __restrict__ src,
                                             unsigned short* __restrict__ dst, int n4) {
    int i = blockIdx.x * 256 + threadIdx.x;
    if (i >= n4) return;
    float4 v = ((const float4*)src)[i];
    ushort4 o;
    o.x = f2b(v.x); o.y = f2b(v.y); o.z = f2b(v.z); o.w = f2b(v.w);
    ((ushort4*)dst)[i] = o;
}

// MODE 0: row sum; MODE 1: row sum of squares. One wave per row (bf16 input).
template <int MODE>
__global__ __launch_bounds__(256) void rowreduce(const unsigned short* __restrict__ X,
                                                 int L, int rows, float* __restrict__ out) {
    int w = threadIdx.x >> 6, lane = threadIdx.x & 63;
    int row = blockIdx.x * 4 + w;
    if (row >= rows) return;
    const unsigned short* xr = X + (size_t)row * L;
    float s = 0.f;
    int passes = L >> 8;
    for (int p = 0; p < passes; ++p) {
        ushort4 u = *(const ushort4*)(xr + (p << 8) + lane * 4);
        float a = b2f(u.x), b = b2f(u.y), c = b2f(u.z), d = b2f(u.w);
        s += MODE ? (a * a + b * b + c * c + d * d) : (a + b + c + d);
    }
#pragma unroll
    for (int o = 32; o > 0; o >>= 1) s += __shfl_down(s, o);
    if (lane == 0) out[row] = s;
}

// row sum of squares over fp8-e4m3 rows (handles Q8||K8 -> q2||k2 in one pass)
__global__ __launch_bounds__(256) void rowreduce8(const unsigned char* __restrict__ X,
                                                  int L, int rows, float* __restrict__ out) {
    int w = threadIdx.x >> 6, lane = threadIdx.x & 63;
    int row = blockIdx.x * 4 + w;
    if (row >= rows) return;
    const unsigned char* xr = X + (size_t)row * L;
    float s = 0.f;
    int passes = L >> 8;
    for (int p = 0; p < passes; ++p) {
        uchar4 u = *(const uchar4*)(xr + (p << 8) + lane * 4);
        float a = f8tof(u.x), b = f8tof(u.y), c = f8tof(u.z), d = f8tof(u.w);
        s += a * a + b * b + c * c + d * d;
    }
#pragma unroll
    for (int o = 32; o > 0; o >>= 1) s += __shfl_down(s, o);
    if (lane == 0) out[row] = s;
}

#define MF(A_, B_, C_) (C_) = __builtin_amdgcn_mfma_f32_16x16x32_bf16((A_), (B_), (C_), 0, 0, 0)
#define MF8(A_, B_, C_) (C_) = __builtin_amdgcn_mfma_f32_16x16x32_fp8_fp8((A_), (B_), (C_), 0, 0, 0)
#define DSR(dst_, a_, imm_) \
    asm volatile("ds_read_b128 %0, %1 offset:" #imm_ : "=v"(dst_) : "v"(a_))
#define DSR64(dst_, a_, imm_) \
    asm volatile("ds_read_b64 %0, %1 offset:" #imm_ : "=v"(dst_) : "v"(a_))
#define GL4(d_, p_) asm volatile("global_load_dwordx4 %0, %1, off" : "=v"(d_) : "v"(p_))
#define DSW(a_, imm_, d_) \
    asm volatile("ds_write_b128 %0, %1 offset:" #imm_ :: "v"(a_), "v"(d_) : "memory")
#define LGKM(n_) asm volatile("s_waitcnt lgkmcnt(" #n_ ")" ::: "memory")
#define VMC0 asm volatile("s_waitcnt vmcnt(0)" ::: "memory")
#define SB0 __builtin_amdgcn_sched_barrier(0)

// ---------------- bf16 GEMM, 128x256/BK=32, 2 blocks/CU ----------------
#define LOADTB(T_) do {                                                    \
    const size_t ko_ = (size_t)(T_) * 32;                                  \
    GL4(ra0, pa + ko_);                                                    \
    GL4(rb0, pb + ko_); GL4(rb1, pb + ldb128 + ko_);                       \
} while (0)
#define WRITETB(WB_) do {                                                  \
    DSW(wAa + ((WB_) >> 1), 0, ra0);                                       \
    DSW(wBb + (WB_), 0, rb0); DSW(wBb + (WB_), 8192, rb1);                 \
} while (0)

// EPI 0: bf16 out. EPI 2: f32 = acc / aux1[row]. EPI 3: fp8-e4m3 out.
template <int EPI>
__global__ __launch_bounds__(512, 4) void gemm128b(
    const unsigned short* __restrict__ A, int lda, long long sA,
    const unsigned short* __restrict__ B, int ldb, long long sB,
    void* __restrict__ Cv, int ldc, long long sC,
    int Kd, int perm,
    const float* __restrict__ aux1, int sAux1) {
    __shared__ __attribute__((aligned(128))) unsigned short As[2 * 128 * 32];  // 16 KB
    __shared__ __attribute__((aligned(128))) unsigned short Bs[2 * 256 * 32];  // 32 KB

    const int z = perm ? blockIdx.x : blockIdx.z;
    const int jb = perm ? blockIdx.y : blockIdx.x;
    const int ib = perm ? blockIdx.z : blockIdx.y;
    const unsigned short* __restrict__ Ab = A + (size_t)z * sA;
    const unsigned short* __restrict__ Bb = B + (size_t)z * sB;
    const int i0 = ib * 128, j0 = jb * 256;
    const int tid = threadIdx.x;
    const int w = tid >> 6, lane = tid & 63;
    const int wr = w >> 2, wc = w & 3;   // 2M x 4N waves, 64x64 C each
    const int c16 = lane & 15, kq = lane >> 4;

    const int srow = tid >> 2;
    const int clog = (tid & 3) ^ ((srow >> 1) & 3);
    const unsigned short* pa = Ab + (size_t)(i0 + srow) * lda + clog * 8;
    const unsigned short* pb = Bb + (size_t)(j0 + srow) * ldb + clog * 8;
    const size_t ldb128 = (size_t)128 * ldb;

    const unsigned wAa = lds_off(As) + (unsigned)tid * 16;
    const unsigned wBb = lds_off(Bs) + (unsigned)tid * 16;

    const int sw = (kq ^ ((c16 >> 1) & 3)) << 4;
    const unsigned adrA0 = lds_off(As) + (unsigned)(wr * 64 + c16) * 64 + sw;
    const unsigned adrB0 = lds_off(Bs) + (unsigned)(wc * 64 + c16) * 64 + sw;

    f32x4 acc[4][4];
    const f32x4 zero = {0.f, 0.f, 0.f, 0.f};
#pragma unroll
    for (int i = 0; i < 4; ++i)
#pragma unroll
        for (int j = 0; j < 4; ++j) acc[i][j] = zero;

    u32x4 ra0, rb0, rb1;
    bf16x8 aF[4], bF[4];

    const int nt = Kd >> 5;

    LOADTB(0);
    VMC0;
    WRITETB(0u);
    LOADTB(1);
    LGKM(0);
    wg_barrier();

    for (int t = 0; t < nt; ++t) {
        const unsigned rb_ = (t & 1) ? 16384u : 0u;
        const unsigned wb_ = (t & 1) ? 0u : 16384u;
        const unsigned aA = adrA0 + (rb_ >> 1);
        const unsigned aB = adrB0 + rb_;
        DSR(aF[0], aA, 0);    DSR(aF[1], aA, 1024);
        DSR(aF[2], aA, 2048); DSR(aF[3], aA, 3072);
        DSR(bF[0], aB, 0);    DSR(bF[1], aB, 1024);
        DSR(bF[2], aB, 2048); DSR(bF[3], aB, 3072);
        if (t + 1 < nt) {
            VMC0;
            WRITETB(wb_);
            if (t + 2 < nt) LOADTB(t + 2);
            LGKM(3);
        } else {
            LGKM(0);
        }
        SB0;
        __builtin_amdgcn_s_setprio(1);
#pragma unroll
        for (int mi = 0; mi < 4; ++mi)
#pragma unroll
            for (int ni = 0; ni < 4; ++ni)
                MF(aF[mi], bF[ni], acc[mi][ni]);
        __builtin_amdgcn_s_setprio(0);
        LGKM(0);
        wg_barrier();
    }

    const int prow = kq * 4;
    if constexpr (EPI == 0) {
        unsigned short* C = (unsigned short*)Cv + (size_t)z * sC;
#pragma unroll
        for (int mi = 0; mi < 4; ++mi)
#pragma unroll
            for (int ni = 0; ni < 4; ++ni) {
                const int row = i0 + wr * 64 + mi * 16 + prow;
                const int col = j0 + wc * 64 + ni * 16 + c16;
#pragma unroll
                for (int r = 0; r < 4; ++r)
                    C[(size_t)(row + r) * ldc + col] = f2b(acc[mi][ni][r]);
            }
    } else if constexpr (EPI == 3) {
        unsigned char* C = (unsigned char*)Cv + (size_t)z * sC;
#pragma unroll
        for (int mi = 0; mi < 4; ++mi)
#pragma unroll
            for (int ni = 0; ni < 4; ++ni) {
                const int row = i0 + wr * 64 + mi * 16 + prow;
                const int col = j0 + wc * 64 + ni * 16 + c16;
#pragma unroll
                for (int r = 0; r < 4; ++r)
                    C[(size_t)(row + r) * ldc + col] = f2f8(acc[mi][ni][r]);
            }
    } else {
        float* C = (float*)Cv + (size_t)z * sC;
        const float* lb = aux1 + (size_t)z * sAux1;
#pragma unroll
        for (int mi = 0; mi < 4; ++mi) {
            const int row = i0 + wr * 64 + mi * 16 + prow;
            float linv[4];
#pragma unroll
            for (int r = 0; r < 4; ++r) linv[r] = 1.0f / lb[row + r];
#pragma unroll
            for (int ni = 0; ni < 4; ++ni) {
                const int col = j0 + wc * 64 + ni * 16 + c16;
#pragma unroll
                for (int r = 0; r < 4; ++r)
                    C[(size_t)(row + r) * ldc + col] = acc[mi][ni][r] * linv[r];
            }
        }
    }
}

// -------- fp8 scores GEMM: BM=128 x BN=128, acc[4][2], 3 blocks/CU --------
#define LOADT8(T_) do {                                                    \
    const size_t ko_ = (size_t)(T_) * 64;                                  \
    GL4(fa0, pa8 + ko_);                                                   \
    GL4(fb0, pb8 + ko_);                                                   \
} while (0)
#define WRITET8(WB_) do {                                                  \
    DSW(wA8 + (WB_), 0, fa0);                                              \
    DSW(wB8 + (WB_), 0, fb0);                                              \
} while (0)

__global__ __launch_bounds__(512, 6) void gemm128f8(
    const unsigned char* __restrict__ A, int lda, long long sA,
    const unsigned char* __restrict__ B, int ldb, long long sB,
    unsigned short* __restrict__ Cq, int ldc, long long sC,
    int Kd,
    const float* __restrict__ q2a, int sQ2,
    const float* __restrict__ k2a, int sK2,
    float invs) {
    __shared__ __attribute__((aligned(128))) unsigned char As8[2 * 128 * 64];  // 16 KB
    __shared__ __attribute__((aligned(128))) unsigned char Bs8[2 * 128 * 64];  // 16 KB

    const int z = blockIdx.x;        // XCD i owns batch i
    const int jb = blockIdx.y, ib = blockIdx.z;
    const unsigned char* __restrict__ Ab = A + (size_t)z * sA;
    const unsigned char* __restrict__ Bb = B + (size_t)z * sB;
    const int i0 = ib * 128, j0 = jb * 128;
    const int tid = threadIdx.x;
    const int w = tid >> 6, lane = tid & 63;
    const int wr = w >> 2, wc = w & 3;   // 2M x 4N waves, 64x32 C each
    const int c16 = lane & 15, kq = lane >> 4;

    const int srow = tid >> 2;           // 0..127
    const int p8 = (tid & 3) ^ (srow & 3) ^ ((srow >> 2) & 1);
    const unsigned char* pa8 = Ab + (size_t)(i0 + srow) * lda + p8 * 16;
    const unsigned char* pb8 = Bb + (size_t)(j0 + srow) * ldb + p8 * 16;

    const unsigned wA8 = lds_off(As8) + (unsigned)tid * 16;
    const unsigned wB8 = lds_off(Bs8) + (unsigned)tid * 16;

    const int gl = (c16 & 3) ^ ((c16 >> 2) & 1);
    const int soff = ((((kq >> 1) ^ gl) << 4) | ((kq & 1) << 3));
    const unsigned adrA80 = lds_off(As8) + (unsigned)(wr * 64 + c16) * 64 + soff;
    const unsigned adrB80 = lds_off(Bs8) + (unsigned)(wc * 32 + c16) * 64 + soff;

    f32x4 acc[4][2];
    const f32x4 zero = {0.f, 0.f, 0.f, 0.f};
#pragma unroll
    for (int i = 0; i < 4; ++i)
#pragma unroll
        for (int j = 0; j < 2; ++j) acc[i][j] = zero;

    u32x4 fa0, fb0;
    long aF[4][2], bF[2][2];

    const int nt = Kd >> 6;  // 12

    LOADT8(0);
    VMC0;
    WRITET8(0u);
    LOADT8(1);
    LGKM(0);
    wg_barrier();

    for (int t = 0; t < nt; ++t) {
        const unsigned rb_ = (t & 1) ? 8192u : 0u;
        const unsigned wb_ = (t & 1) ? 0u : 8192u;
        const unsigned aA = adrA80 + rb_, aAx = aA ^ 32u;
        const unsigned aB = adrB80 + rb_, aBx = aB ^ 32u;
        DSR64(aF[0][0], aA, 0);    DSR64(aF[0][1], aAx, 0);
        DSR64(aF[1][0], aA, 1024); DSR64(aF[1][1], aAx, 1024);
        DSR64(aF[2][0], aA, 2048); DSR64(aF[2][1], aAx, 2048);
        DSR64(aF[3][0], aA, 3072); DSR64(aF[3][1], aAx, 3072);
        DSR64(bF[0][0], aB, 0);    DSR64(bF[0][1], aBx, 0);
        DSR64(bF[1][0], aB, 1024); DSR64(bF[1][1], aBx, 1024);
        if (t + 1 < nt) {
            VMC0;
            WRITET8(wb_);
            if (t + 2 < nt) LOADT8(t + 2);
            LGKM(2);
        } else {
            LGKM(0);
        }
        SB0;
        __builtin_amdgcn_s_setprio(1);
#pragma unroll
        for (int kk = 0; kk < 2; ++kk)
#pragma unroll
            for (int mi = 0; mi < 4; ++mi)
#pragma unroll
                for (int ni = 0; ni < 2; ++ni)
                    MF8(aF[mi][kk], bF[ni][kk], acc[mi][ni]);
        __builtin_amdgcn_s_setprio(0);
        LGKM(0);
        wg_barrier();
    }

    // scores epilogue: E -> bf16 via per-wave transpose (16x40 shorts in dead As8)
    unsigned short* C = Cq + (size_t)z * sC;
    const float* q2b = q2a + (size_t)z * sQ2;
    const float* k2b = k2a + (size_t)z * sK2;
    unsigned short* sc = (unsigned short*)(As8 + w * 2048);
    const int prow = kq * 4;
    const int rr = lane >> 2, ch = lane & 3;
#pragma unroll
    for (int mi = 0; mi < 4; ++mi) {
#pragma unroll
        for (int ni = 0; ni < 2; ++ni) {
            const int col = j0 + wc * 32 + ni * 16 + c16;
            const float k2v = k2b[col];
#pragma unroll
            for (int r = 0; r < 4; ++r) {
                const int grow = i0 + wr * 64 + mi * 16 + prow + r;
                float d2 = q2b[grow] + k2v - 2.0f * acc[mi][ni][r];
                float e = __expf(sqrtf(fmaxf(d2, 0.f)) * invs);
                sc[(prow + r) * 40 + ni * 16 + c16] = f2b(e);
            }
        }
        bf16x8 v = *(const bf16x8*)&sc[rr * 40 + ch * 8];
        const int grow = i0 + wr * 64 + mi * 16 + rr;
        *(bf16x8*)&C[(size_t)grow * ldc + j0 + wc * 32 + ch * 8] = v;
    }
}

extern "C" void kernel_launch(void* const* d_in, const int* in_sizes, int n_in,
                              void* d_out, int out_size, void* d_ws, size_t ws_size,
                              hipStream_t stream) {
    const float* x = (const float*)d_in[0];
    const float* Wq = (const float*)d_in[1];
    const float* Wk = (const float*)d_in[2];
    const float* Wv = (const float*)d_in[3];
    const int Bz = 8, S = 2048, D = 768, F = 768;
    const int BS = Bz * S;  // 16384

    const size_t szX = (size_t)BS * D * 2;
    const size_t szW = (size_t)F * D * 2;
    const size_t szQ8 = (size_t)BS * F;
    const size_t szE = (size_t)Bz * S * S * 2;

    char* p = (char*)d_ws;
    unsigned short* xb = (unsigned short*)p;  p += szX;
    unsigned short* Wqb = (unsigned short*)p; p += szW;
    unsigned short* Wkb = (unsigned short*)p; p += szW;
    unsigned short* Wvb = (unsigned short*)p; p += szW;
    unsigned char* Q8 = (unsigned char*)p;    p += szQ8;  // Q8 || K8 contiguous
    unsigned char* K8 = (unsigned char*)p;    p += szQ8;
    unsigned short* VT = (unsigned short*)p;  p += szX;   // [F][BS]
    unsigned short* E = (unsigned short*)p;   p += szE;   // [Bz][S][S]
    float* q2 = (float*)p;    p += (size_t)BS * 4;        // q2 || k2 contiguous
    float* k2 = (float*)p;    p += (size_t)BS * 4;
    float* lsum = (float*)p;  p += (size_t)BS * 4;
    if ((size_t)(p - (char*)d_ws) > ws_size) return;  // ~147 MiB scratch required

    const float invs = 1.0f / sqrtf(768.0f);

    // 1) casts
    castk<<<(BS * D / 4 + 255) / 256, 256, 0, stream>>>(x, xb, BS * D / 4);
    castk<<<(F * D / 4 + 255) / 256, 256, 0, stream>>>(Wq, Wqb, F * D / 4);
    castk<<<(F * D / 4 + 255) / 256, 256, 0, stream>>>(Wk, Wkb, F * D / 4);
    castk<<<(F * D / 4 + 255) / 256, 256, 0, stream>>>(Wv, Wvb, F * D / 4);

    // 2) Q8,K8 = e4m3(x . W^T)  (z=0 -> Wq->Q8, z=1 -> Wk->K8); 768 blocks
    gemm128b<3><<<dim3(F / 256, BS / 128, 2), 512, 0, stream>>>(
        xb, D, 0,
        Wqb, D, (long long)F * D,
        Q8, F, (long long)BS * F,
        D, 0, nullptr, 0);

    //    V^T = Wv . x^T -> VT[f][s] (bf16); 384 blocks
    gemm128b<0><<<dim3(BS / 256, F / 128, 1), 512, 0, stream>>>(
        Wvb, D, 0,
        xb, D, 0,
        VT, BS, 0,
        D, 0, nullptr, 0);

    // 3) q2||k2 from fp8-rounded Q8||K8 in ONE dispatch (both contiguous)
    rowreduce8<<<2 * BS / 4, 256, 0, stream>>>(Q8, F, 2 * BS, q2);

    // 4) E; x=batch -> XCD-pinned; (8,16,16) = 2048 blocks
    gemm128f8<<<dim3(Bz, S / 128, S / 128), 512, 0, stream>>>(
        Q8, F, (long long)S * F,
        K8, F, (long long)S * F,
        E, S, (long long)S * S,
        F, q2, S, k2, S, invs);

    // 5) l = rowsum(E)
    rowreduce<0><<<BS / 4, 256, 0, stream>>>(E, S, BS, lsum);

    // 6) out = (E . V) / l; x=batch -> XCD-pinned; 384 blocks
    gemm128b<2><<<dim3(Bz, F / 256, S / 128), 512, 0, stream>>>(
        E, S, (long long)S * S,
        VT, BS, (long long)S,
        d_out, F, (long long)S * F,
        S, 1, lsum, S);
}